// Round 2
// baseline (57.075 us; speedup 1.0000x reference)
//
#include <hip/hip_runtime.h>

// Exact-rounding 3-component squared sum in reference order: (x*x + y*y) + z*z
static __device__ __forceinline__ float sq3(float x, float y, float z) {
    return __fadd_rn(__fadd_rn(__fmul_rn(x, x), __fmul_rn(y, y)), __fmul_rn(z, z));
}

// ---------------- Kernel 1: H_i per row (one thread per row) ----------------
__global__ __launch_bounds__(256) void h_kernel(
    const float* __restrict__ X,
    float* __restrict__ outH,
    int N, int rows)
{
    const float EPS   = 0.001f;
    const float LENNH = 1.015f;

    int row = blockIdx.x * blockDim.x + threadIdx.x;
    if (row >= rows) return;
    int i = row & (N - 1);

    const float* xi = X + (size_t)row * 12;
    float4 a4 = *(const float4*)xi;        // N.x N.y N.z Ca.x   (16B aligned)
    float2 a2 = *(const float2*)(xi + 4);  // Ca.y Ca.z          (8B aligned)
    float nx = a4.x, ny = a4.y, nz = a4.z;
    float cax = a4.w, cay = a2.x, caz = a2.y;

    int prow = (i == 0) ? row : row - 1;
    const float* xp = X + (size_t)prow * 12;
    float2 p2 = *(const float2*)(xp + 6);  // Cprev.x Cprev.y    (8B aligned)
    float px = p2.x, py = p2.y, pz = xp[8];

    // u1 = normed(N - Cprev)
    float ax = __fsub_rn(nx, px), ay = __fsub_rn(ny, py), az = __fsub_rn(nz, pz);
    float s1 = __fsqrt_rn(__fadd_rn(sq3(ax, ay, az), EPS));
    ax = __fdiv_rn(ax, s1); ay = __fdiv_rn(ay, s1); az = __fdiv_rn(az, s1);
    // u2 = normed(N - Ca)
    float bx = __fsub_rn(nx, cax), by = __fsub_rn(ny, cay), bz = __fsub_rn(nz, caz);
    float s2 = __fsqrt_rn(__fadd_rn(sq3(bx, by, bz), EPS));
    bx = __fdiv_rn(bx, s2); by = __fdiv_rn(by, s2); bz = __fdiv_rn(bz, s2);
    // u = normed(u1 + u2)
    float ux = __fadd_rn(ax, bx), uy = __fadd_rn(ay, by), uz = __fadd_rn(az, bz);
    float s3 = __fsqrt_rn(__fadd_rn(sq3(ux, uy, uz), EPS));
    ux = __fdiv_rn(ux, s3); uy = __fdiv_rn(uy, s3); uz = __fdiv_rn(uz, s3);

    float* ho = outH + (size_t)row * 3;
    ho[0] = __fadd_rn(nx, __fmul_rn(LENNH, ux));
    ho[1] = __fadd_rn(ny, __fmul_rn(LENNH, uy));
    ho[2] = __fadd_rn(nz, __fmul_rn(LENNH, uz));
}

// ---------------- Kernel 2: per-edge (one wave per row, lane = k) ----------------
__global__ __launch_bounds__(256) void edge_kernel(
    const float* __restrict__ X,
    const int*   __restrict__ C,
    const int*   __restrict__ E,
    const float* __restrict__ M,
    const float* __restrict__ H,   // = outH, written by h_kernel
    float* __restrict__ outHB,
    float* __restrict__ outMK,
    int N, int rows)
{
    const float EPS   = 0.001f;
    const float COEFF = (float)(0.42 * 0.2 * 332.0);   // 27.888f

    int tid = blockIdx.x * blockDim.x + threadIdx.x;
    int row = tid >> 6;
    if (row >= rows) return;
    int k = tid & 63;
    int i = row & (N - 1);
    int b = row >> 14;

    // Row-uniform values: force scalar path via readfirstlane
    int urow = __builtin_amdgcn_readfirstlane(row);
    const float* xi = X + (size_t)urow * 12;
    float nx = xi[0], ny = xi[1], nz = xi[2];
    const float* hi = H + (size_t)urow * 3;
    float hx = hi[0], hy = hi[1], hz = hi[2];
    int Ci = C[urow];

    // ---- per-edge ----
    size_t eoff = (size_t)row * 64 + (size_t)k;
    int j = E[eoff];
    float mij = M[eoff];

    const float* xj = X + ((size_t)b * (size_t)N + (size_t)j) * 12;
    float2 cj01 = *(const float2*)(xj + 6);   // C_j.x C_j.y (8B aligned)
    float4 v4   = *(const float4*)(xj + 8);   // C_j.z O_j.xyz (16B aligned)
    float cjx = cj01.x, cjy = cj01.y, cjz = v4.x;
    float ojx = v4.y,   ojy = v4.z,   ojz = v4.w;

    float dx = __fsub_rn(nx, ojx), dy = __fsub_rn(ny, ojy), dz = __fsub_rn(nz, ojz);
    float dno = __fsqrt_rn(__fadd_rn(sq3(dx, dy, dz), EPS));
    float iNO = __fdiv_rn(1.0f, dno);
    dx = __fsub_rn(nx, cjx); dy = __fsub_rn(ny, cjy); dz = __fsub_rn(nz, cjz);
    float iNC = __fdiv_rn(1.0f, __fsqrt_rn(__fadd_rn(sq3(dx, dy, dz), EPS)));
    dx = __fsub_rn(hx, cjx); dy = __fsub_rn(hy, cjy); dz = __fsub_rn(hz, cjz);
    float iHC = __fdiv_rn(1.0f, __fsqrt_rn(__fadd_rn(sq3(dx, dy, dz), EPS)));
    dx = __fsub_rn(hx, ojx); dy = __fsub_rn(hy, ojy); dz = __fsub_rn(hz, ojz);
    float iHO = __fdiv_rn(1.0f, __fsqrt_rn(__fadd_rn(sq3(dx, dy, dz), EPS)));

    float U = __fmul_rn(COEFF, __fsub_rn(__fadd_rn(__fsub_rn(iNO, iNC), iHC), iHO));

    int Cn = C[(size_t)b * (size_t)N + (size_t)j];
    int dij = j - i; if (dij < 0) dij = -dij;

    float m_local    = ((dij < 3) && (Ci == Cn)) ? 1.0f : 0.0f;
    float m_nonlocal = __fsub_rn(1.0f, m_local);
    float m_cutD     = (dno < 3.6f) ? 1.0f : 0.0f;
    float m_i        = (Ci > 0) ? 1.0f : 0.0f;     // C_prev == C identically
    float m_int      = __fmul_rn(m_i, (Cn > 0) ? 1.0f : 0.0f);

    float mhb = __fmul_rn(__fmul_rn(__fmul_rn(mij, m_nonlocal), m_cutD), m_int);
    float hb  = __fmul_rn(mhb, (U < -0.5f) ? 1.0f : 0.0f);

    outHB[eoff] = hb;
    outMK[eoff] = mhb;
}

extern "C" void kernel_launch(void* const* d_in, const int* in_sizes, int n_in,
                              void* d_out, int out_size, void* d_ws, size_t ws_size,
                              hipStream_t stream) {
    const float* X = (const float*)d_in[0];
    const int*   C = (const int*)d_in[1];
    const int*   E = (const int*)d_in[2];
    const float* M = (const float*)d_in[3];

    int rows = in_sizes[1];          // B*N = 65536
    int BNK  = in_sizes[2];          // B*N*K = 4194304
    const int N = 16384;

    float* out   = (float*)d_out;
    float* outHB = out;
    float* outMK = out + (size_t)BNK;
    float* outH  = out + 2 * (size_t)BNK;

    {
        int block = 256;
        int grid  = (rows + block - 1) / block;
        hipLaunchKernelGGL(h_kernel, dim3(grid), dim3(block), 0, stream,
                           X, outH, N, rows);
    }
    {
        int total = rows * 64;
        int block = 256;
        int grid  = (total + block - 1) / block;
        hipLaunchKernelGGL(edge_kernel, dim3(grid), dim3(block), 0, stream,
                           X, C, E, M, outH, outHB, outMK, N, rows);
    }
}

// Round 3
// 36.311 us; speedup vs baseline: 1.5718x; 1.5718x over previous
//
#include <hip/hip_runtime.h>

// Exact-rounding 3-component squared sum in reference order: (x*x + y*y) + z*z
static __device__ __forceinline__ float sq3(float x, float y, float z) {
    return __fadd_rn(__fadd_rn(__fmul_rn(x, x), __fmul_rn(y, y)), __fmul_rn(z, z));
}

// ---------------- Kernel 1: per-row H_i + packed gather table ----------------
// T[2*row]   = (Cjx, Cjy, Cjz, Ojx)
// T[2*row+1] = (Ojy, Ojz, asfloat(C[row]), 0)
__global__ __launch_bounds__(256) void setup_kernel(
    const float* __restrict__ X,
    const int*   __restrict__ C,
    float*  __restrict__ outH,
    float4* __restrict__ T,        // may be null (fallback mode)
    int N, int rows)
{
    const float EPS   = 0.001f;
    const float LENNH = 1.015f;

    int row = blockIdx.x * blockDim.x + threadIdx.x;
    if (row >= rows) return;
    int i = row & (N - 1);

    const float* xi = X + (size_t)row * 12;
    float4 a4  = *(const float4*)xi;        // N.xyz, Ca.x
    float2 a2  = *(const float2*)(xi + 4);  // Ca.y, Ca.z
    float2 c01 = *(const float2*)(xi + 6);  // C.x, C.y
    float4 co  = *(const float4*)(xi + 8);  // C.z, O.xyz
    float nx = a4.x, ny = a4.y, nz = a4.z;
    float cax = a4.w, cay = a2.x, caz = a2.y;

    if (T) {
        T[2 * (size_t)row]     = make_float4(c01.x, c01.y, co.x, co.y);
        T[2 * (size_t)row + 1] = make_float4(co.z, co.w, __int_as_float(C[row]), 0.0f);
    }

    int prow = (i == 0) ? row : row - 1;
    const float* xp = X + (size_t)prow * 12;
    float2 p2 = *(const float2*)(xp + 6);
    float px = p2.x, py = p2.y, pz = xp[8];

    // u1 = normed(N - Cprev)
    float ax = __fsub_rn(nx, px), ay = __fsub_rn(ny, py), az = __fsub_rn(nz, pz);
    float s1 = __fsqrt_rn(__fadd_rn(sq3(ax, ay, az), EPS));
    ax = __fdiv_rn(ax, s1); ay = __fdiv_rn(ay, s1); az = __fdiv_rn(az, s1);
    // u2 = normed(N - Ca)
    float bx = __fsub_rn(nx, cax), by = __fsub_rn(ny, cay), bz = __fsub_rn(nz, caz);
    float s2 = __fsqrt_rn(__fadd_rn(sq3(bx, by, bz), EPS));
    bx = __fdiv_rn(bx, s2); by = __fdiv_rn(by, s2); bz = __fdiv_rn(bz, s2);
    // u = normed(u1 + u2)
    float ux = __fadd_rn(ax, bx), uy = __fadd_rn(ay, by), uz = __fadd_rn(az, bz);
    float s3 = __fsqrt_rn(__fadd_rn(sq3(ux, uy, uz), EPS));
    ux = __fdiv_rn(ux, s3); uy = __fdiv_rn(uy, s3); uz = __fdiv_rn(uz, s3);

    float* ho = outH + (size_t)row * 3;
    ho[0] = __fadd_rn(nx, __fmul_rn(LENNH, ux));
    ho[1] = __fadd_rn(ny, __fmul_rn(LENNH, uy));
    ho[2] = __fadd_rn(nz, __fmul_rn(LENNH, uz));
}

// Per-edge math, bit-exact reference order.
static __device__ __forceinline__ void edge_math(
    float nx, float ny, float nz, float hx, float hy, float hz,
    int Ci, int i, int j, float mij, float4 t0, float4 t1,
    float& hb, float& mhb)
{
    const float EPS   = 0.001f;
    const float COEFF = (float)(0.42 * 0.2 * 332.0);   // 27.888f

    float cjx = t0.x, cjy = t0.y, cjz = t0.z;
    float ojx = t0.w, ojy = t1.x, ojz = t1.y;
    int   Cn  = __float_as_int(t1.z);

    float dx = __fsub_rn(nx, ojx), dy = __fsub_rn(ny, ojy), dz = __fsub_rn(nz, ojz);
    float dno = __fsqrt_rn(__fadd_rn(sq3(dx, dy, dz), EPS));
    float iNO = __fdiv_rn(1.0f, dno);
    dx = __fsub_rn(nx, cjx); dy = __fsub_rn(ny, cjy); dz = __fsub_rn(nz, cjz);
    float iNC = __fdiv_rn(1.0f, __fsqrt_rn(__fadd_rn(sq3(dx, dy, dz), EPS)));
    dx = __fsub_rn(hx, cjx); dy = __fsub_rn(hy, cjy); dz = __fsub_rn(hz, cjz);
    float iHC = __fdiv_rn(1.0f, __fsqrt_rn(__fadd_rn(sq3(dx, dy, dz), EPS)));
    dx = __fsub_rn(hx, ojx); dy = __fsub_rn(hy, ojy); dz = __fsub_rn(hz, ojz);
    float iHO = __fdiv_rn(1.0f, __fsqrt_rn(__fadd_rn(sq3(dx, dy, dz), EPS)));

    float U = __fmul_rn(COEFF, __fsub_rn(__fadd_rn(__fsub_rn(iNO, iNC), iHC), iHO));

    int dij = j - i; if (dij < 0) dij = -dij;
    float m_local    = ((dij < 3) && (Ci == Cn)) ? 1.0f : 0.0f;
    float m_nonlocal = __fsub_rn(1.0f, m_local);
    float m_cutD     = (dno < 3.6f) ? 1.0f : 0.0f;
    float m_i        = (Ci > 0) ? 1.0f : 0.0f;
    float m_int      = __fmul_rn(m_i, (Cn > 0) ? 1.0f : 0.0f);

    mhb = __fmul_rn(__fmul_rn(__fmul_rn(mij, m_nonlocal), m_cutD), m_int);
    hb  = __fmul_rn(mhb, (U < -0.5f) ? 1.0f : 0.0f);
}

// ---------------- Kernel 2: 4 edges per thread via packed table ----------------
__global__ __launch_bounds__(256) void edge_kernel4(
    const int*   __restrict__ C,
    const int*   __restrict__ E,
    const float* __restrict__ M,
    const float* __restrict__ H,
    const float* __restrict__ X,
    const float4* __restrict__ T,
    float* __restrict__ outHB,
    float* __restrict__ outMK,
    int N, int rows)
{
    int tid = blockIdx.x * blockDim.x + threadIdx.x;   // rows*16 threads
    int row = tid >> 4;
    if (row >= rows) return;
    int k0 = (tid & 15) << 2;
    int i = row & (N - 1);
    int b = row >> 14;

    const float* xi = X + (size_t)row * 12;
    float nx = xi[0], ny = xi[1], nz = xi[2];
    const float* hi = H + (size_t)row * 3;
    float hx = hi[0], hy = hi[1], hz = hi[2];
    int Ci = C[row];

    size_t eoff = (size_t)row * 64 + (size_t)k0;
    int4   j4 = *(const int4*)(E + eoff);
    float4 m4 = *(const float4*)(M + eoff);

    const float4* Tb = T + ((size_t)b << 15);   // 2*N float4 per batch
    // Issue all 8 gather loads up front for MLP.
    float4 t0a = Tb[2 * (size_t)j4.x],     t1a = Tb[2 * (size_t)j4.x + 1];
    float4 t0b = Tb[2 * (size_t)j4.y],     t1b = Tb[2 * (size_t)j4.y + 1];
    float4 t0c = Tb[2 * (size_t)j4.z],     t1c = Tb[2 * (size_t)j4.z + 1];
    float4 t0d = Tb[2 * (size_t)j4.w],     t1d = Tb[2 * (size_t)j4.w + 1];

    float4 hbv, mkv;
    edge_math(nx, ny, nz, hx, hy, hz, Ci, i, j4.x, m4.x, t0a, t1a, hbv.x, mkv.x);
    edge_math(nx, ny, nz, hx, hy, hz, Ci, i, j4.y, m4.y, t0b, t1b, hbv.y, mkv.y);
    edge_math(nx, ny, nz, hx, hy, hz, Ci, i, j4.z, m4.z, t0c, t1c, hbv.z, mkv.z);
    edge_math(nx, ny, nz, hx, hy, hz, Ci, i, j4.w, m4.w, t0d, t1d, hbv.w, mkv.w);

    *(float4*)(outHB + eoff) = hbv;
    *(float4*)(outMK + eoff) = mkv;
}

// ---------------- Fallback kernel (no workspace): R2 path, known-good ----------------
__global__ __launch_bounds__(256) void edge_kernel_noT(
    const float* __restrict__ X,
    const int*   __restrict__ C,
    const int*   __restrict__ E,
    const float* __restrict__ M,
    const float* __restrict__ H,
    float* __restrict__ outHB,
    float* __restrict__ outMK,
    int N, int rows)
{
    int tid = blockIdx.x * blockDim.x + threadIdx.x;
    int row = tid >> 6;
    if (row >= rows) return;
    int k = tid & 63;
    int i = row & (N - 1);
    int b = row >> 14;

    int urow = __builtin_amdgcn_readfirstlane(row);
    const float* xi = X + (size_t)urow * 12;
    float nx = xi[0], ny = xi[1], nz = xi[2];
    const float* hi = H + (size_t)urow * 3;
    float hx = hi[0], hy = hi[1], hz = hi[2];
    int Ci = C[urow];

    size_t eoff = (size_t)row * 64 + (size_t)k;
    int j = E[eoff];
    float mij = M[eoff];

    const float* xj = X + ((size_t)b * (size_t)N + (size_t)j) * 12;
    float2 cj01 = *(const float2*)(xj + 6);
    float4 v4   = *(const float4*)(xj + 8);
    int Cn = C[(size_t)b * (size_t)N + (size_t)j];

    float4 t0 = make_float4(cj01.x, cj01.y, v4.x, v4.y);
    float4 t1 = make_float4(v4.z, v4.w, __int_as_float(Cn), 0.0f);
    float hb, mhb;
    edge_math(nx, ny, nz, hx, hy, hz, Ci, i, j, mij, t0, t1, hb, mhb);

    outHB[eoff] = hb;
    outMK[eoff] = mhb;
}

extern "C" void kernel_launch(void* const* d_in, const int* in_sizes, int n_in,
                              void* d_out, int out_size, void* d_ws, size_t ws_size,
                              hipStream_t stream) {
    const float* X = (const float*)d_in[0];
    const int*   C = (const int*)d_in[1];
    const int*   E = (const int*)d_in[2];
    const float* M = (const float*)d_in[3];

    int rows = in_sizes[1];          // B*N = 65536
    int BNK  = in_sizes[2];          // B*N*K
    const int N = 16384;

    float* out   = (float*)d_out;
    float* outHB = out;
    float* outMK = out + (size_t)BNK;
    float* outH  = out + 2 * (size_t)BNK;

    size_t tbytes = (size_t)rows * 32;
    bool useT = (ws_size >= tbytes) && (d_ws != nullptr);
    float4* T = useT ? (float4*)d_ws : nullptr;

    {
        int block = 256;
        int grid  = (rows + block - 1) / block;
        hipLaunchKernelGGL(setup_kernel, dim3(grid), dim3(block), 0, stream,
                           X, C, outH, T, N, rows);
    }
    if (useT) {
        int total = rows * 16;
        int block = 256;
        int grid  = (total + block - 1) / block;
        hipLaunchKernelGGL(edge_kernel4, dim3(grid), dim3(block), 0, stream,
                           C, E, M, outH, X, T, outHB, outMK, N, rows);
    } else {
        int total = rows * 64;
        int block = 256;
        int grid  = (total + block - 1) / block;
        hipLaunchKernelGGL(edge_kernel_noT, dim3(grid), dim3(block), 0, stream,
                           X, C, E, M, outH, outHB, outMK, N, rows);
    }
}